// Round 1
// baseline (305.077 us; speedup 1.0000x reference)
//
#include <hip/hip_runtime.h>

// Retrace loss, chunked affine-scan.
//
// R4 redesign: rounds 1-3 established that scattered per-(b,d) loads are fatal
// and LDS staging of ALL five arrays fixes coalescing but pins occupancy at
// 3 blocks/CU (43 KB LDS) -> latency-bound at 20% HBM, VALUBusy 11%, occ 7.4%.
// Fix: only Q, base, g need the LDS transpose. eQ/tQ/rw/tpp are elementwise
// inputs to base/g -> load them coalesced into REGISTERS, compute base/g
// vectorized, write just (base,g) pairs + Q to LDS. LDS drops 43 KB -> 25.1 KB
// (6 blocks/CU), exp2/fmin leave the serial scan, and one barrier per block.
//
// Windows are shifted so every chunk stages exactly `rows` rows per array:
//   e/tQ/tpp/bpp staged from t0+1 (scan step i uses shifted row i)
//   rw/Q staged from t0 (scan step i uses row i)
// rows = 32 (last chunk: 31; step j=511 doesn't exist). No OOB: last shifted
// row is t=511.
//
// Per-step arithmetic sequence is IDENTICAL to the previous kernel (same fp
// ops, same order) -> chunk summaries bitwise equal -> phase2 unchanged.

constexpr int B  = 2048;
constexpr int T  = 512;
constexpr int D  = 16;
constexpr int NC = 16;             // time chunks
constexpr int CS = 32;             // scan steps per chunk (last chunk: 31)
constexpr int BPB = 4;             // b-values per block
constexpr int SQ = B * (D / 4);    // 8192 sequence-quads (ws layout unit)
constexpr float GAMMA = 0.99f;
constexpr float LOG2E = 1.44269504088896340736f;

// LDS geometry. Pads of 16 floats put consecutive bl-groups on opposite
// 16-bank halves -> scan reads are 2-way (free) or conflict-free.
constexpr int QSEG  = CS * D + 16;        // 528 floats per (Q, b)
constexpr int BGSEG = CS * D * 2 + 16;    // 1040 floats per (base|g interleaved, b)
constexpr int LDS_FLOATS = BPB * QSEG + BPB * BGSEG;   // 6272 floats = 25.1 KB

__device__ __forceinline__ void load_lds16(const float* g, float* l) {
    __builtin_amdgcn_global_load_lds(
        (const __attribute__((address_space(1))) unsigned int*)g,
        (__attribute__((address_space(3))) unsigned int*)l, 16, 0, 0);
}

__global__ __launch_bounds__(64, 2) void retrace_phase1(
    const float* __restrict__ Q,
    const float* __restrict__ eQ,
    const float* __restrict__ tQ,
    const float* __restrict__ rw,
    const float* __restrict__ tpp,
    const float* __restrict__ bpp,
    float* __restrict__ ws)
{
    __shared__ __align__(16) float lds[LDS_FLOATS];
    float* lQ  = lds;                    // [BPB][QSEG]
    float* lBG = lds + BPB * QSEG;       // [BPB][BGSEG], floats (base,g) per (t,d)

    const int tid = threadIdx.x;           // 0..63
    const int k   = blockIdx.y;            // chunk
    const int b0  = blockIdx.x * BPB;
    const int t0  = k * CS;

    const bool last = (k == NC - 1);
    const int rows = last ? (CS - 1) : CS; // 31 | 32 staged rows AND scan steps
    const int n4   = rows * (D / 4);       // 124 | 128 float4 per (array, b)

    // ---- (1) coalesced register loads: shifted e/tq/tpp/bpp, unshifted rw ----
    float4 ev4[BPB][2], tq4[BPB][2], tp4[BPB][2], rv4[BPB][2];
    float  bpv[BPB][2];
    #pragma unroll
    for (int bl = 0; bl < BPB; ++bl) {
        const size_t rb = ((size_t)(b0 + bl) * T + t0) * (D / 4); // float4 index
        const float4* ge = (const float4*)eQ  + rb + (D / 4);
        const float4* gt = (const float4*)tQ  + rb + (D / 4);
        const float4* gp = (const float4*)tpp + rb + (D / 4);
        const float4* gr = (const float4*)rw  + rb;
        const float*  gb = bpp + (size_t)(b0 + bl) * T + t0 + 1;
        #pragma unroll
        for (int h = 0; h < 2; ++h) {
            const int off = tid + 64 * h;
            if (off < n4) {
                ev4[bl][h] = ge[off];
                tq4[bl][h] = gt[off];
                tp4[bl][h] = gp[off];
                rv4[bl][h] = gr[off];
                bpv[bl][h] = gb[off >> 2];   // broadcast across the 4 d of one t
            }
        }
    }

    // ---- (2) Q: direct global->LDS, 1 KB contiguous per instruction ----
    #pragma unroll
    for (int bl = 0; bl < BPB; ++bl) {
        const float* gq = Q + ((size_t)(b0 + bl) * T + t0) * D;
        float* l = lQ + bl * QSEG;
        #pragma unroll
        for (int h = 0; h < 2; ++h) {
            const int off = tid + 64 * h;
            if (off < n4) load_lds16(gq + (size_t)off * 4, l + (size_t)off * 4);
        }
    }

    // ---- (3) compute (base, g) vectorized; write interleaved pairs to LDS ----
    // Identical per-element fp sequence to the old scan body:
    //   cw = exp2(min(tp-bp,0)*LOG2E); g = GAMMA*cw;
    //   base = fma(-g, tq, fma(GAMMA, ev, rv))
    #pragma unroll
    for (int bl = 0; bl < BPB; ++bl) {
        float* lbg = lBG + bl * BGSEG;
        #pragma unroll
        for (int h = 0; h < 2; ++h) {
            const int off = tid + 64 * h;
            if (off < n4) {
                const float* e = (const float*)&ev4[bl][h];
                const float* t = (const float*)&tq4[bl][h];
                const float* p = (const float*)&tp4[bl][h];
                const float* r = (const float*)&rv4[bl][h];
                const float bp = bpv[bl][h];
                float bg[8];
                #pragma unroll
                for (int j = 0; j < 4; ++j) {
                    const float cw = __builtin_exp2f(fminf(p[j] - bp, 0.f) * LOG2E);
                    const float g  = GAMMA * cw;
                    bg[2 * j]     = fmaf(-g, t[j], fmaf(GAMMA, e[j], r[j]));
                    bg[2 * j + 1] = g;
                }
                float4* dst = (float4*)(lbg + (size_t)off * 8);
                dst[0] = make_float4(bg[0], bg[1], bg[2], bg[3]);
                dst[1] = make_float4(bg[4], bg[5], bg[6], bg[7]);
            }
        }
    }

    __syncthreads();   // drains vmcnt (Q global_load_lds) + lgkm (bg writes)

    // ---- (4) scan from LDS: thread (bl, d), descending i over the chunk ----
    const int bl = tid >> 4;
    const int d  = tid & 15;
    const float* sQ  = lQ  + bl * QSEG + d;
    const float* sBG = lBG + bl * BGSEG + 2 * d;

    float alpha = 0.f, beta = 1.f, P = 0.f, S = 0.f, W = 0.f;
    #pragma unroll 8
    for (int i = rows - 1; i >= 0; --i) {
        const float2 bg = *(const float2*)(sBG + 32 * i);  // (base, g)
        const float qv  = sQ[i * D];
        const float g   = bg.y;
        alpha = fmaf(g, alpha, bg.x);
        beta  = g * beta;
        const float u = qv - alpha;
        P = fmaf(u, u, P);
        S = fmaf(u, beta, S);
        W = fmaf(beta, beta, W);
    }

    // ---- Store chunk summary: 64 consecutive floats per (k, b-group) ----
    const size_t AS = (size_t)NC * SQ * 4;          // floats per ws sub-array
    const size_t o  = ((size_t)k * SQ + (size_t)b0 * 4) * 4 + tid;
    ws[0 * AS + o] = alpha;
    ws[1 * AS + o] = beta;
    ws[2 * AS + o] = P;
    ws[3 * AS + o] = S;
    ws[4 * AS + o] = W;
}

__global__ __launch_bounds__(64) void retrace_phase2(
    const float* __restrict__ tQ,
    const float4* __restrict__ ws,
    float* __restrict__ out)
{
    const int s  = blockIdx.x * blockDim.x + threadIdx.x;  // 0..SQ-1
    const int b  = s >> 2;
    const int dq = s & 3;

    const float4* wsA = ws;
    const float4* wsM = ws + (size_t)NC * SQ;
    const float4* wsP = ws + (size_t)2 * NC * SQ;
    const float4* wsS = ws + (size_t)3 * NC * SQ;
    const float4* wsW = ws + (size_t)4 * NC * SQ;

    float4 c4 = ((const float4*)tQ)[((size_t)b * T + (T - 1)) * 4 + dq];
    float* c = (float*)&c4;
    float loss[4] = {0.f, 0.f, 0.f, 0.f};

    #pragma unroll
    for (int k = NC - 1; k >= 0; --k) {
        const size_t o = (size_t)k * SQ + s;
        const float4 A4 = wsA[o], M4 = wsM[o], P4 = wsP[o], S4 = wsS[o], W4 = wsW[o];
        const float* A = (const float*)&A4;
        const float* M = (const float*)&M4;
        const float* P = (const float*)&P4;
        const float* S = (const float*)&S4;
        const float* W = (const float*)&W4;
        #pragma unroll
        for (int i = 0; i < 4; ++i) {
            loss[i] += fmaf(c[i], fmaf(W[i], c[i], -2.f * S[i]), P[i]);
            c[i] = fmaf(M[i], c[i], A[i]);
        }
    }

    float acc = (loss[0] + loss[1]) + (loss[2] + loss[3]);
    #pragma unroll
    for (int off = 32; off > 0; off >>= 1)
        acc += __shfl_down(acc, off, 64);

    if (threadIdx.x == 0) {
        constexpr float inv_count = 1.0f / ((float)B * (float)(T - 1) * (float)D);
        atomicAdd(out, acc * inv_count);
    }
}

extern "C" void kernel_launch(void* const* d_in, const int* in_sizes, int n_in,
                              void* d_out, int out_size, void* d_ws, size_t ws_size,
                              hipStream_t stream) {
    const float* Q   = (const float*)d_in[0];
    const float* eQ  = (const float*)d_in[1];
    const float* tQ  = (const float*)d_in[2];
    const float* rw  = (const float*)d_in[3];
    const float* tpp = (const float*)d_in[4];
    const float* bpp = (const float*)d_in[5];
    float* out = (float*)d_out;
    float* ws = (float*)d_ws;   // 5 * NC * SQ * 16 B = 10.5 MB

    hipMemsetAsync(out, 0, sizeof(float), stream);

    // Phase 1: 512 x 16 single-wave blocks; LDS 25.1 KB -> 6 blocks/CU.
    retrace_phase1<<<dim3(B / BPB, NC), dim3(64), 0, stream>>>(
        Q, eQ, tQ, rw, tpp, bpp, ws);

    // Phase 2: chains 16 chunk summaries per sequence.
    retrace_phase2<<<dim3(SQ / 64), dim3(64), 0, stream>>>(tQ, (const float4*)ws, out);
}

// Round 4
// 302.825 us; speedup vs baseline: 1.0074x; 1.0074x over previous
//
#include <hip/hip_runtime.h>

// Retrace loss, chunked affine-scan.
//
// R7 == R6 == R5 resubmit (two container-acquisition failures, no data; source
// re-audited: no OOB, no capture-unsafe calls -- infra, not kernel).
// R5: R4's occupancy fix (43->25 KB LDS, 3->6 blk/CU) did NOT help (124 vs 114
// us) and VALUBusy FELL to 6.8% -> phase1 is not occupancy-bound. Counter
// accounting: per-block latency ~45K cyc, of which ~600 VALU and ~1.2K
// vmem-in-flight; the rest is lgkm stalls -- the scan reads LDS one element at
// a time against a serial fma chain (~64 reads x ~120 cyc single-outstanding
// LDS latency). Fixes:
//  (1) scan reads batched: preload 16 steps of (base,g,q) into statically-
//      indexed register arrays before the serial chain (template<int N> for
//      the 15-step tail so indices stay compile-time).
//  (2) grid remapped 1-D, k-inner: 16 temporally-adjacent blocks cover a
//      contiguous 128 KB span per array (was 2 KB islands at 32 KB stride)
//      for DRAM row locality.
// Per-step fp sequence identical to R4 -> chunk summaries bitwise equal.

constexpr int B  = 2048;
constexpr int T  = 512;
constexpr int D  = 16;
constexpr int NC = 16;             // time chunks
constexpr int CS = 32;             // scan steps per chunk (last chunk: 31)
constexpr int BPB = 4;             // b-values per block
constexpr int SQ = B * (D / 4);    // 8192 sequence-quads (ws layout unit)
constexpr float GAMMA = 0.99f;
constexpr float LOG2E = 1.44269504088896340736f;

constexpr int QSEG  = CS * D + 16;        // 528 floats per (Q, b)
constexpr int BGSEG = CS * D * 2 + 16;    // 1040 floats per (base|g interleaved, b)
constexpr int LDS_FLOATS = BPB * QSEG + BPB * BGSEG;   // 6272 floats = 25.1 KB

__device__ __forceinline__ void load_lds16(const float* g, float* l) {
    __builtin_amdgcn_global_load_lds(
        (const __attribute__((address_space(1))) unsigned int*)g,
        (__attribute__((address_space(3))) unsigned int*)l, 16, 0, 0);
}

struct ScanState { float alpha, beta, P, S, W; };

// Preload N steps (i0..i0+N-1) of (base,g) and q into registers with
// compile-time indexing, then run the serial chain descending. One lgkm wait
// amortized over N steps instead of one per read.
template<int N>
__device__ __forceinline__ void scan_batch(const float* __restrict__ sBG,
                                           const float* __restrict__ sQ,
                                           const int i0, ScanState& st) {
    float2 bg[N];
    float  q[N];
    #pragma unroll
    for (int j = 0; j < N; ++j) {
        bg[j] = *(const float2*)(sBG + 32 * (i0 + j));
        q[j]  = sQ[(i0 + j) * D];
    }
    #pragma unroll
    for (int j = N - 1; j >= 0; --j) {
        const float g = bg[j].y;
        st.alpha = fmaf(g, st.alpha, bg[j].x);
        st.beta  = g * st.beta;
        const float u = q[j] - st.alpha;
        st.P = fmaf(u, u, st.P);
        st.S = fmaf(u, st.beta, st.S);
        st.W = fmaf(st.beta, st.beta, st.W);
    }
}

__global__ __launch_bounds__(64, 2) void retrace_phase1(
    const float* __restrict__ Q,
    const float* __restrict__ eQ,
    const float* __restrict__ tQ,
    const float* __restrict__ rw,
    const float* __restrict__ tpp,
    const float* __restrict__ bpp,
    float* __restrict__ ws)
{
    __shared__ __align__(16) float lds[LDS_FLOATS];
    float* lQ  = lds;                    // [BPB][QSEG]
    float* lBG = lds + BPB * QSEG;       // [BPB][BGSEG], (base,g) pairs per (t,d)

    const int tid = threadIdx.x;           // 0..63
    const int bid = blockIdx.x;
    const int k   = bid & (NC - 1);        // k-inner: adjacent blocks ->
    const int b0  = (bid >> 4) * BPB;      // contiguous address spans
    const int t0  = k * CS;

    const bool last = (k == NC - 1);
    const int rows = last ? (CS - 1) : CS; // 31 | 32 staged rows AND scan steps
    const int n4   = rows * (D / 4);       // 124 | 128 float4 per (array, b)

    // ---- (1) coalesced register loads: shifted e/tq/tpp/bpp, unshifted rw ----
    float4 ev4[BPB][2], tq4[BPB][2], tp4[BPB][2], rv4[BPB][2];
    float  bpv[BPB][2];
    #pragma unroll
    for (int bl = 0; bl < BPB; ++bl) {
        const size_t rb = ((size_t)(b0 + bl) * T + t0) * (D / 4); // float4 index
        const float4* ge = (const float4*)eQ  + rb + (D / 4);
        const float4* gt = (const float4*)tQ  + rb + (D / 4);
        const float4* gp = (const float4*)tpp + rb + (D / 4);
        const float4* gr = (const float4*)rw  + rb;
        const float*  gb = bpp + (size_t)(b0 + bl) * T + t0 + 1;
        #pragma unroll
        for (int h = 0; h < 2; ++h) {
            const int off = tid + 64 * h;
            if (off < n4) {
                ev4[bl][h] = ge[off];
                tq4[bl][h] = gt[off];
                tp4[bl][h] = gp[off];
                rv4[bl][h] = gr[off];
                bpv[bl][h] = gb[off >> 2];   // broadcast across the 4 d of one t
            }
        }
    }

    // ---- (2) Q: direct global->LDS, 1 KB contiguous per instruction ----
    #pragma unroll
    for (int bl = 0; bl < BPB; ++bl) {
        const float* gq = Q + ((size_t)(b0 + bl) * T + t0) * D;
        float* l = lQ + bl * QSEG;
        #pragma unroll
        for (int h = 0; h < 2; ++h) {
            const int off = tid + 64 * h;
            if (off < n4) load_lds16(gq + (size_t)off * 4, l + (size_t)off * 4);
        }
    }

    // ---- (3) compute (base, g) vectorized; write interleaved pairs to LDS ----
    //   cw = exp2(min(tp-bp,0)*LOG2E); g = GAMMA*cw;
    //   base = fma(-g, tq, fma(GAMMA, ev, rv))
    #pragma unroll
    for (int bl = 0; bl < BPB; ++bl) {
        float* lbg = lBG + bl * BGSEG;
        #pragma unroll
        for (int h = 0; h < 2; ++h) {
            const int off = tid + 64 * h;
            if (off < n4) {
                const float* e = (const float*)&ev4[bl][h];
                const float* t = (const float*)&tq4[bl][h];
                const float* p = (const float*)&tp4[bl][h];
                const float* r = (const float*)&rv4[bl][h];
                const float bp = bpv[bl][h];
                float bg[8];
                #pragma unroll
                for (int j = 0; j < 4; ++j) {
                    const float cw = __builtin_exp2f(fminf(p[j] - bp, 0.f) * LOG2E);
                    const float g  = GAMMA * cw;
                    bg[2 * j]     = fmaf(-g, t[j], fmaf(GAMMA, e[j], r[j]));
                    bg[2 * j + 1] = g;
                }
                float4* dst = (float4*)(lbg + (size_t)off * 8);
                dst[0] = make_float4(bg[0], bg[1], bg[2], bg[3]);
                dst[1] = make_float4(bg[4], bg[5], bg[6], bg[7]);
            }
        }
    }

    __syncthreads();   // drains vmcnt (global_load_lds) + lgkm (bg writes)

    // ---- (4) scan from LDS, batched preloads: thread (bl, d) ----
    const int bl = tid >> 4;
    const int d  = tid & 15;
    const float* sQ  = lQ  + bl * QSEG + d;
    const float* sBG = lBG + bl * BGSEG + 2 * d;

    ScanState st = {0.f, 1.f, 0.f, 0.f, 0.f};
    if (last) scan_batch<15>(sBG, sQ, 16, st);   // i = 30..16
    else      scan_batch<16>(sBG, sQ, 16, st);   // i = 31..16
    scan_batch<16>(sBG, sQ, 0, st);              // i = 15..0

    // ---- Store chunk summary: 64 consecutive floats per (k, b-group) ----
    const size_t AS = (size_t)NC * SQ * 4;          // floats per ws sub-array
    const size_t o  = ((size_t)k * SQ + (size_t)b0 * 4) * 4 + tid;
    ws[0 * AS + o] = st.alpha;
    ws[1 * AS + o] = st.beta;
    ws[2 * AS + o] = st.P;
    ws[3 * AS + o] = st.S;
    ws[4 * AS + o] = st.W;
}

__global__ __launch_bounds__(64) void retrace_phase2(
    const float* __restrict__ tQ,
    const float4* __restrict__ ws,
    float* __restrict__ out)
{
    const int s  = blockIdx.x * blockDim.x + threadIdx.x;  // 0..SQ-1
    const int b  = s >> 2;
    const int dq = s & 3;

    const float4* wsA = ws;
    const float4* wsM = ws + (size_t)NC * SQ;
    const float4* wsP = ws + (size_t)2 * NC * SQ;
    const float4* wsS = ws + (size_t)3 * NC * SQ;
    const float4* wsW = ws + (size_t)4 * NC * SQ;

    float4 c4 = ((const float4*)tQ)[((size_t)b * T + (T - 1)) * 4 + dq];
    float* c = (float*)&c4;
    float loss[4] = {0.f, 0.f, 0.f, 0.f};

    #pragma unroll
    for (int k = NC - 1; k >= 0; --k) {
        const size_t o = (size_t)k * SQ + s;
        const float4 A4 = wsA[o], M4 = wsM[o], P4 = wsP[o], S4 = wsS[o], W4 = wsW[o];
        const float* A = (const float*)&A4;
        const float* M = (const float*)&M4;
        const float* P = (const float*)&P4;
        const float* S = (const float*)&S4;
        const float* W = (const float*)&W4;
        #pragma unroll
        for (int i = 0; i < 4; ++i) {
            loss[i] += fmaf(c[i], fmaf(W[i], c[i], -2.f * S[i]), P[i]);
            c[i] = fmaf(M[i], c[i], A[i]);
        }
    }

    float acc = (loss[0] + loss[1]) + (loss[2] + loss[3]);
    #pragma unroll
    for (int off = 32; off > 0; off >>= 1)
        acc += __shfl_down(acc, off, 64);

    if (threadIdx.x == 0) {
        constexpr float inv_count = 1.0f / ((float)B * (float)(T - 1) * (float)D);
        atomicAdd(out, acc * inv_count);
    }
}

extern "C" void kernel_launch(void* const* d_in, const int* in_sizes, int n_in,
                              void* d_out, int out_size, void* d_ws, size_t ws_size,
                              hipStream_t stream) {
    const float* Q   = (const float*)d_in[0];
    const float* eQ  = (const float*)d_in[1];
    const float* tQ  = (const float*)d_in[2];
    const float* rw  = (const float*)d_in[3];
    const float* tpp = (const float*)d_in[4];
    const float* bpp = (const float*)d_in[5];
    float* out = (float*)d_out;
    float* ws = (float*)d_ws;   // 5 * NC * SQ * 16 B = 10.5 MB

    hipMemsetAsync(out, 0, sizeof(float), stream);

    // Phase 1: 8192 single-wave blocks, 1-D k-inner mapping; 25.1 KB LDS.
    retrace_phase1<<<dim3(B / BPB * NC), dim3(64), 0, stream>>>(
        Q, eQ, tQ, rw, tpp, bpp, ws);

    // Phase 2: chains 16 chunk summaries per sequence.
    retrace_phase2<<<dim3(SQ / 64), dim3(64), 0, stream>>>(tQ, (const float4*)ws, out);
}

// Round 6
// 302.305 us; speedup vs baseline: 1.0092x; 1.0017x over previous
//
#include <hip/hip_runtime.h>

// Retrace loss — single fused persistent kernel.
//
// R9 == R8 resubmit (container-acquisition failure, no data; source re-audited:
// pipeline rotation consistent, chunk-15 guard complete, COMBINE bit-identical
// to phase2, launch graph-capture-safe -- infra, not kernel).
//
// R8 rationale. Evidence through R7: (a) total 300-305us while phase1 is only
// 114-124us in EVERY structural variant -> ~183us lives in phase2 (128 blocks
// = 0.5 waves/CU latency straggler reading the 10.5MB ws round-trip) + extra
// dispatches; (b) phase1 BW pinned at ~1.55TB/s because VGPR=88 (from
// launch_bounds(64,2)) forces the allocator to serialize staging into
// load->wait->use batches: in-flight bytes/CU ~= BW x latency ~= 5KB ~= ONE
// outstanding wave-load. Occupancy/batching/grid-order knobs were all nulls
// because none lifted this cap.
//
// Fix: fuse everything into one persistent kernel. 512 blocks (one per
// 4-b group, 2/CU), each walks chunks k=15..0 carrying (c, loss) in-register:
//  - no phase2, no ws traffic (21MB), no memset-ordered dispatch chain;
//  - launch_bounds(64,1): ~400 VGPRs legal -> depth-2 prefetch pipeline:
//      unit(j): issue raw loads(j-2) | scan chunk j from LDS | stage(j-1)
//    keeps ~10KB/wave in flight (2 waves/CU ~ 20KB -> supports ~5.7TB/s);
//  - all 5 arrays staged global->reg->LDS (no global_load_lds): with 1 wave
//    per block every LDS hazard is same-wave ds_write->ds_read, ordered by
//    compiler waitcnts exactly -> NO barriers anywhere.
// Per-chunk fp sequence identical to R7 phase1; cross-chunk combine identical
// to phase2's per-(b,d) scalar chain.

constexpr int B  = 2048;
constexpr int T  = 512;
constexpr int D  = 16;
constexpr int NC = 16;             // time chunks
constexpr int CS = 32;             // scan steps per chunk (last chunk: 31)
constexpr int BPB = 4;             // b-values per block
constexpr float GAMMA = 0.99f;
constexpr float LOG2E = 1.44269504088896340736f;

constexpr int QSEG  = CS * D + 16;        // 528 floats per (Q, b)
constexpr int BGSEG = CS * D * 2 + 16;    // 1040 floats per (base|g pairs, b)
constexpr int BUFSZ = BPB * (QSEG + BGSEG);   // 6272 floats per chunk buffer
constexpr int LDS_FLOATS = 2 * BUFSZ;         // 50.2 KB

struct ScanState { float alpha, beta, P, S, W; };

// Raw per-chunk staged data: 5 arrays x [BPB][2] float4 + bpp rows. ~168 regs.
struct Raw {
    float4 ev[BPB][2], tq[BPB][2], tp[BPB][2], rv[BPB][2], qv[BPB][2];
    float  bp[BPB][2];
};

// Issue all global loads for chunk k into R (no waits here; consumed at stage).
// GUARD=true only for chunk 15 (rows=31 -> off<124; shifted arrays would be
// OOB at off>=124).
template<bool GUARD>
__device__ __forceinline__ void issue_loads(
    const int k, Raw& R, const int b0, const int tid,
    const float* __restrict__ Q,  const float* __restrict__ eQ,
    const float* __restrict__ tQ, const float* __restrict__ rw,
    const float* __restrict__ tpp, const float* __restrict__ bpp)
{
    const int t0 = k * CS;
    #pragma unroll
    for (int bl = 0; bl < BPB; ++bl) {
        const size_t rb = ((size_t)(b0 + bl) * T + t0) * (D / 4); // float4 idx
        const float4* gq = (const float4*)Q   + rb;
        const float4* ge = (const float4*)eQ  + rb + (D / 4);     // t0+1 shift
        const float4* gt = (const float4*)tQ  + rb + (D / 4);
        const float4* gp = (const float4*)tpp + rb + (D / 4);
        const float4* gr = (const float4*)rw  + rb;
        const float*  gb = bpp + (size_t)(b0 + bl) * T + t0 + 1;
        #pragma unroll
        for (int h = 0; h < 2; ++h) {
            const int off = tid + 64 * h;
            if (!GUARD || off < (CS - 1) * (D / 4)) {
                R.qv[bl][h] = gq[off];
                R.ev[bl][h] = ge[off];
                R.tq[bl][h] = gt[off];
                R.tp[bl][h] = gp[off];
                R.rv[bl][h] = gr[off];
                R.bp[bl][h] = gb[off >> 2];
            }
        }
    }
}

// Consume R: compute (base,g) and ds_write bg + Q pass-through into buf.
// (Chunk-15 tail lanes write garbage into rows >=31 of the buffer; scan31
// never reads them.)
__device__ __forceinline__ void stage(const Raw& R, float* __restrict__ buf,
                                      const int tid)
{
    float* lQ  = buf;
    float* lBG = buf + BPB * QSEG;
    #pragma unroll
    for (int bl = 0; bl < BPB; ++bl) {
        #pragma unroll
        for (int h = 0; h < 2; ++h) {
            const int off = tid + 64 * h;
            const float* e = (const float*)&R.ev[bl][h];
            const float* t = (const float*)&R.tq[bl][h];
            const float* p = (const float*)&R.tp[bl][h];
            const float* r = (const float*)&R.rv[bl][h];
            const float bp = R.bp[bl][h];
            float bg[8];
            #pragma unroll
            for (int j = 0; j < 4; ++j) {
                const float cw = __builtin_exp2f(fminf(p[j] - bp, 0.f) * LOG2E);
                const float g  = GAMMA * cw;
                bg[2 * j]     = fmaf(-g, t[j], fmaf(GAMMA, e[j], r[j]));
                bg[2 * j + 1] = g;
            }
            float4* dst = (float4*)(lBG + bl * BGSEG + (size_t)off * 8);
            dst[0] = make_float4(bg[0], bg[1], bg[2], bg[3]);
            dst[1] = make_float4(bg[4], bg[5], bg[6], bg[7]);
            *(float4*)(lQ + bl * QSEG + (size_t)off * 4) = R.qv[bl][h];
        }
    }
}

// Batched scan: preload N steps into statically-indexed regs, then the serial
// chain. Same fp sequence as R4-R7.
template<int N>
__device__ __forceinline__ void scan_batch(const float* __restrict__ sBG,
                                           const float* __restrict__ sQ,
                                           const int i0, ScanState& st) {
    float2 bg[N];
    float  q[N];
    #pragma unroll
    for (int j = 0; j < N; ++j) {
        bg[j] = *(const float2*)(sBG + 32 * (i0 + j));
        q[j]  = sQ[(i0 + j) * D];
    }
    #pragma unroll
    for (int j = N - 1; j >= 0; --j) {
        const float g = bg[j].y;
        st.alpha = fmaf(g, st.alpha, bg[j].x);
        st.beta  = g * st.beta;
        const float u = q[j] - st.alpha;
        st.P = fmaf(u, u, st.P);
        st.S = fmaf(u, st.beta, st.S);
        st.W = fmaf(st.beta, st.beta, st.W);
    }
}

template<bool LAST>  // LAST=true -> 31 steps (chunk 15)
__device__ __forceinline__ ScanState scan_chunk(const float* __restrict__ buf,
                                                const int tid) {
    const int bl = tid >> 4;
    const int d  = tid & 15;
    const float* sQ  = buf + bl * QSEG + d;
    const float* sBG = buf + BPB * QSEG + bl * BGSEG + 2 * d;
    ScanState st = {0.f, 1.f, 0.f, 0.f, 0.f};
    if (LAST) scan_batch<15>(sBG, sQ, 16, st);   // i = 30..16
    else      scan_batch<16>(sBG, sQ, 16, st);   // i = 31..16
    scan_batch<16>(sBG, sQ, 0, st);              // i = 15..0
    return st;
}

#define COMBINE() do { \
    loss = fmaf(c, fmaf(st.W, c, -2.f * st.S), st.P) + loss; \
    c = fmaf(st.beta, c, st.alpha); \
} while (0)

__global__ __launch_bounds__(64, 1) void retrace_fused(
    const float* __restrict__ Q,
    const float* __restrict__ eQ,
    const float* __restrict__ tQ,
    const float* __restrict__ rw,
    const float* __restrict__ tpp,
    const float* __restrict__ bpp,
    float* __restrict__ out)
{
    __shared__ __align__(16) float lds[LDS_FLOATS];
    float* buf0 = lds;
    float* buf1 = lds + BUFSZ;

    const int tid = threadIdx.x;           // 0..63
    const int b0  = blockIdx.x * BPB;

    // Scan-lane identity (bl,d); carry init from tQ[:, T-1, :].
    const int bl_l = tid >> 4, d_l = tid & 15;
    float c = tQ[((size_t)(b0 + bl_l) * T + (T - 1)) * D + d_l];
    float loss = 0.f;

    Raw R0, R1;   // raw(x) lives in R[x&1]

    // ---- prologue: fill pipeline ----
    issue_loads<true >(15, R1, b0, tid, Q, eQ, tQ, rw, tpp, bpp);
    issue_loads<false>(14, R0, b0, tid, Q, eQ, tQ, rw, tpp, bpp);
    stage(R1, buf1, tid);                       // chunk 15 -> buf1
    // peeled unit 15:
    issue_loads<false>(13, R1, b0, tid, Q, eQ, tQ, rw, tpp, bpp);
    ScanState st = scan_chunk<true>(buf1, tid); // 31 steps
    COMBINE();
    stage(R0, buf0, tid);                       // chunk 14 -> buf0

    // ---- main loop: units (j even, j-1 odd), j = 14,12,...,2 ----
    for (int j = 14; j >= 2; j -= 2) {
        // unit j (even): raw(j-1) in R1 arrived; issue j-2 into R0.
        issue_loads<false>(j - 2, R0, b0, tid, Q, eQ, tQ, rw, tpp, bpp);
        st = scan_chunk<false>(buf0, tid);      // chunk j
        COMBINE();
        stage(R1, buf1, tid);                   // chunk j-1 -> buf1
        // unit j-1 (odd): issue j-3 into R1 (skip when j-3 < 0).
        if (j >= 4)
            issue_loads<false>(j - 3, R1, b0, tid, Q, eQ, tQ, rw, tpp, bpp);
        st = scan_chunk<false>(buf1, tid);      // chunk j-1
        COMBINE();
        stage(R0, buf0, tid);                   // chunk j-2 -> buf0
    }

    // ---- epilogue: chunk 0 (staged into buf0 by the last loop body) ----
    st = scan_chunk<false>(buf0, tid);
    loss = fmaf(c, fmaf(st.W, c, -2.f * st.S), st.P) + loss;

    // ---- reduce 64 lanes, one atomic per block ----
    float acc = loss;
    #pragma unroll
    for (int off = 32; off > 0; off >>= 1)
        acc += __shfl_down(acc, off, 64);
    if (tid == 0) {
        constexpr float inv_count = 1.0f / ((float)B * (float)(T - 1) * (float)D);
        atomicAdd(out, acc * inv_count);
    }
}

extern "C" void kernel_launch(void* const* d_in, const int* in_sizes, int n_in,
                              void* d_out, int out_size, void* d_ws, size_t ws_size,
                              hipStream_t stream) {
    const float* Q   = (const float*)d_in[0];
    const float* eQ  = (const float*)d_in[1];
    const float* tQ  = (const float*)d_in[2];
    const float* rw  = (const float*)d_in[3];
    const float* tpp = (const float*)d_in[4];
    const float* bpp = (const float*)d_in[5];
    float* out = (float*)d_out;
    (void)d_ws; (void)ws_size;

    hipMemsetAsync(out, 0, sizeof(float), stream);

    // 512 persistent single-wave blocks (2/CU), each owns 4 b-values and
    // walks all 16 chunks with an in-register depth-2 prefetch pipeline.
    retrace_fused<<<dim3(B / BPB), dim3(64), 0, stream>>>(
        Q, eQ, tQ, rw, tpp, bpp, out);
}